// Round 4
// baseline (223.135 us; speedup 1.0000x reference)
//
#include <hip/hip_runtime.h>
#include <math.h>

#define B_SZ 16384
#define F_N 39
#define V_N 30000
#define D_N 16
#define K_SEL 20
#define FD 624     // F_N * D_N
#define KP0 640    // controller/GEMM0 K padded to multiple of 32
#define NCP 48     // controller GEMM padded N (>= 39, 3 n-tiles of 16)
#define N0 1024
#define N1 512
#define CBR 64     // batch rows per fused-controller block (1 wave = 16 rows)
#define ALD 648    // LDS row stride (u16)

typedef unsigned short u16;
typedef __attribute__((ext_vector_type(8))) short bf16x8;
typedef __attribute__((ext_vector_type(8))) unsigned short u16x8;
typedef __attribute__((ext_vector_type(4))) float f32x4;

__device__ __forceinline__ u16 f2bf(float v) {
    union { float f; unsigned u; } x; x.f = v;
    unsigned r = x.u + 0x7fff + ((x.u >> 16) & 1);   // RNE
    return (u16)(r >> 16);
}
__device__ __forceinline__ float bf2f(u16 v) {
    union { unsigned u; float f; } x; x.u = ((unsigned)v) << 16;
    return x.f;
}
// HW packed convert: D[15:0]=bf16(a), D[31:16]=bf16(b), RNE.
__device__ __forceinline__ unsigned cvtpk2(float a, float b) {
    unsigned d;
    asm("v_cvt_pk_bf16_f32 %0, %1, %2" : "=v"(d) : "v"(a), "v"(b));
    return d;
}

#define GLD16(gp, lp) __builtin_amdgcn_global_load_lds( \
    (const __attribute__((address_space(1))) unsigned int*)(gp), \
    (__attribute__((address_space(3))) unsigned int*)(lp), 16, 0, 0)

// ---------------------------------------------------------------------------
// prep (coalesced): segment by blockIdx.
//   [0,128)   w0 permute via LDS (8 rows/block)
//   [128,134) wc permute
//   [134,390) w1 straight convert
//   [390,398) outp zeroing
//   398       bn param vectors
// ---------------------------------------------------------------------------
__global__ __launch_bounds__(256) void prep_all_kernel(
    const float* __restrict__ w0, const float* __restrict__ w1,
    const float* __restrict__ w_c, const float* __restrict__ b_c,
    const float* __restrict__ g_c, const float* __restrict__ be_c,
    u16* __restrict__ w0b, u16* __restrict__ w1b, u16* __restrict__ wcb,
    float* __restrict__ bcp, float* __restrict__ gcp, float* __restrict__ becp,
    float* __restrict__ outp)
{
    __shared__ float Lb[8][624];
    const int bid = blockIdx.x;
    const int t   = threadIdx.x;

    if (bid < 134) {                       // w0 (bid<128) or wc permute
        const bool is_w0 = (bid < 128);
        const int r0 = is_w0 ? bid * 8 : (bid - 128) * 8;
        const int nrows_src = is_w0 ? N0 : F_N;
        const float* __restrict__ src = is_w0 ? w0 : w_c;
        u16* __restrict__ dst = is_w0 ? w0b : wcb;

        for (int j = t; j < 8 * 156; j += 256) {
            const int row = j / 156;
            const int c4  = j - row * 156;
            const int n   = r0 + row;
            if (n < nrows_src)
                *(float4*)&Lb[row][c4 * 4] =
                    *(const float4*)&src[(size_t)n * FD + c4 * 4];
        }
        __syncthreads();

        for (int j = t; j < 8 * 320; j += 256) {
            const int row = j / 320;
            const int pr  = j - row * 320;
            const int n   = r0 + row;
            const int k0  = pr * 2;
            float v0 = 0.f, v1 = 0.f;
            if (n < nrows_src) {
                const int d0 = k0 & 15,       f0 = k0 >> 4;
                const int d1 = (k0 + 1) & 15, f1 = (k0 + 1) >> 4;
                if (f0 < F_N) v0 = Lb[row][d0 * F_N + f0];
                if (f1 < F_N) v1 = Lb[row][d1 * F_N + f1];
            }
            *(unsigned*)&dst[(size_t)n * KP0 + k0] = cvtpk2(v0, v1);
        }
        return;
    }
    if (bid < 390) {                       // w1 convert
        const size_t e0 = (size_t)(bid - 134) * 2048 + t * 8;
        float4 v0 = *(const float4*)(w1 + e0);
        float4 v1 = *(const float4*)(w1 + e0 + 4);
        uint4 o = { cvtpk2(v0.x, v0.y), cvtpk2(v0.z, v0.w),
                    cvtpk2(v1.x, v1.y), cvtpk2(v1.z, v1.w) };
        *(uint4*)(w1b + e0) = o;
        return;
    }
    if (bid < 398) {                       // outp zero
        const size_t e0 = (size_t)(bid - 390) * 2048 + t * 8;
        float4 z = {0.f, 0.f, 0.f, 0.f};
        *(float4*)(outp + e0)     = z;
        *(float4*)(outp + e0 + 4) = z;
        return;
    }
    if (t < 3 * NCP) {
        const int which = t / NCP, n = t - which * NCP;
        float v = 0.f;
        if (n < F_N) v = (which == 0) ? b_c[n] : (which == 1) ? g_c[n] : be_c[n];
        ((which == 0) ? bcp : (which == 1) ? gcp : becp)[n] = v;
    }
}

// ---------------------------------------------------------------------------
// Fused controller, CBR=64: block = 64 batch rows; gather -> ONE sync; then
// each wave owns 16 rows end-to-end (full-K MFMA, bn, softmax, top-K rank,
// select-scale -> zb). No split-K, no cross-wave reduce, no part[] LDS.
// 256 blocks, 1 block/CU (105 KB LDS).
// ---------------------------------------------------------------------------
__global__ __launch_bounds__(256) void fused_controller_kernel(
    const int* __restrict__ x, const float* __restrict__ emb_table,
    const u16* __restrict__ wcb, const float* __restrict__ bcp,
    const float* __restrict__ gcp, const float* __restrict__ becp,
    u16* __restrict__ zb)
{
    __shared__ __align__(16) u16 Al[CBR * ALD];   // 82944 B
    __shared__ float vv[CBR][49];                 // 12544 B
    __shared__ float selw[CBR][F_N];              //  9984 B

    const int t    = threadIdx.x;
    const int wave = t >> 6;
    const int lane = t & 63;
    const int b0   = blockIdx.x * CBR;

    // ---- gather: 2496 rows, 10 slots/thread, x-loads hoisted for MLP ----
    {
        int xi[10];
        #pragma unroll
        for (int s = 0; s < 10; ++s) {
            const int p = t + s * 256;
            xi[s] = (p < CBR * F_N) ? x[b0 * F_N + p] : 0;
        }
        #pragma unroll
        for (int s = 0; s < 10; ++s) {
            const int p = t + s * 256;
            if (p < CBR * F_N) {
                const int row = p / F_N;
                const int f   = p - row * F_N;
                const float4* src =
                    (const float4*)(emb_table + (size_t)(xi[s] + f * V_N) * D_N);
                float4 v0 = src[0], v1 = src[1], v2 = src[2], v3 = src[3];
                uint4 o0 = { cvtpk2(v0.x, v0.y), cvtpk2(v0.z, v0.w),
                             cvtpk2(v1.x, v1.y), cvtpk2(v1.z, v1.w) };
                uint4 o1 = { cvtpk2(v2.x, v2.y), cvtpk2(v2.z, v2.w),
                             cvtpk2(v3.x, v3.y), cvtpk2(v3.z, v3.w) };
                *(uint4*)&Al[row * ALD + f * D_N]     = o0;
                *(uint4*)&Al[row * ALD + f * D_N + 8] = o1;
            }
        }
    }
    __syncthreads();   // the only block-wide sync

    // ---- per-wave MFMA over its 16 rows, full K=640 ----
    const int m = lane & 15;
    const int q = lane >> 4;
    const int rbase = wave * 16;           // this wave's row slab
    f32x4 acc0 = {}, acc1 = {}, acc2 = {};
    {
        const u16* ap  = &Al[(rbase + m) * ALD + q * 8];
        const u16* bp0 = wcb + (size_t)(0  + m) * KP0 + q * 8;
        const u16* bp1 = wcb + (size_t)(16 + m) * KP0 + q * 8;
        const u16* bp2 = wcb + (size_t)(32 + m) * KP0 + q * 8;
        #pragma unroll
        for (int k = 0; k < 20; ++k) {
            bf16x8 af = *(const bf16x8*)ap;
            bf16x8 b0 = *(const bf16x8*)bp0;
            bf16x8 b1 = *(const bf16x8*)bp1;
            bf16x8 b2 = *(const bf16x8*)bp2;
            acc0 = __builtin_amdgcn_mfma_f32_16x16x32_bf16(af, b0, acc0, 0, 0, 0);
            acc1 = __builtin_amdgcn_mfma_f32_16x16x32_bf16(af, b1, acc1, 0, 0, 0);
            acc2 = __builtin_amdgcn_mfma_f32_16x16x32_bf16(af, b2, acc2, 0, 0, 0);
            ap += 32; bp0 += 32; bp1 += 32; bp2 += 32;
        }
    }

    // bn + relu -> vv (batch row = rbase + q*4 + r, field col = j*16 + m)
    {
        const float rs = rsqrtf(1.0f + 1e-5f);
        #pragma unroll
        for (int j = 0; j < 3; ++j) {
            const f32x4 a = (j == 0) ? acc0 : (j == 1) ? acc1 : acc2;
            const int n = j * 16 + m;
            const float gn = gcp[n] * rs;
            const float bn = becp[n];
            const float bi = bcp[n];
            #pragma unroll
            for (int r = 0; r < 4; ++r)
                vv[rbase + q * 4 + r][n] = fmaxf(fmaf(gn, a[r] + bi, bn), 0.f);
        }
    }

    // ---- per-wave softmax + top-K rank, 4 rows per pass x 4 passes ----
    for (int pass = 0; pass < 4; ++pass) {
        const int row = rbase + pass * 4 + (lane >> 4);
        const int fl  = lane & 15;
        float e[3] = {0.f, 0.f, 0.f};
        float mloc = -1e30f;
        #pragma unroll
        for (int it = 0; it < 3; ++it) {
            const int f = fl + 16 * it;
            if (f < F_N) { e[it] = vv[row][f]; mloc = fmaxf(mloc, e[it]); }
        }
        mloc = fmaxf(mloc, __shfl_xor(mloc, 1, 64));
        mloc = fmaxf(mloc, __shfl_xor(mloc, 2, 64));
        mloc = fmaxf(mloc, __shfl_xor(mloc, 4, 64));
        mloc = fmaxf(mloc, __shfl_xor(mloc, 8, 64));
        float sloc = 0.f;
        #pragma unroll
        for (int it = 0; it < 3; ++it) {
            const int f = fl + 16 * it;
            if (f < F_N) { e[it] = expf(e[it] - mloc); sloc += e[it]; }
        }
        sloc += __shfl_xor(sloc, 1, 64);
        sloc += __shfl_xor(sloc, 2, 64);
        sloc += __shfl_xor(sloc, 4, 64);
        sloc += __shfl_xor(sloc, 8, 64);
        const float inv = 1.f / sloc;
        #pragma unroll
        for (int it = 0; it < 3; ++it) {
            const int f = fl + 16 * it;
            if (f < F_N) vv[row][f] = e[it];
        }

        int rank[3] = {};
        for (int gg = 0; gg < F_N; ++gg) {
            const float o = vv[row][gg];
            #pragma unroll
            for (int it = 0; it < 3; ++it) {
                const int f = fl + 16 * it;
                if (f < F_N)
                    rank[it] += (o > e[it] || (o == e[it] && gg < f)) ? 1 : 0;
            }
        }
        #pragma unroll
        for (int it = 0; it < 3; ++it) {
            const int f = fl + 16 * it;
            if (f < F_N)
                selw[row][f] = (rank[it] < K_SEL) ? e[it] * inv : 0.f;
        }
    }

    // ---- per-wave zb write: its 16 rows x 40 slots, coalesced ----
    for (int gp = lane; gp < 16 * 40; gp += 64) {
        const int row  = gp / 40;
        const int slot = gp - row * 40;
        const int gr   = rbase + row;
        u16* dst = zb + (size_t)(b0 + gr) * KP0 + slot * D_N;
        uint4 o0 = {0u,0u,0u,0u}, o1 = {0u,0u,0u,0u};
        if (slot < F_N) {
            const float w = selw[gr][slot];
            u16x8 a0 = *(u16x8*)&Al[gr * ALD + slot * D_N];
            u16x8 a1 = *(u16x8*)&Al[gr * ALD + slot * D_N + 8];
            o0 = (uint4){ cvtpk2(bf2f(a0[0]) * w, bf2f(a0[1]) * w),
                          cvtpk2(bf2f(a0[2]) * w, bf2f(a0[3]) * w),
                          cvtpk2(bf2f(a0[4]) * w, bf2f(a0[5]) * w),
                          cvtpk2(bf2f(a0[6]) * w, bf2f(a0[7]) * w) };
            o1 = (uint4){ cvtpk2(bf2f(a1[0]) * w, bf2f(a1[1]) * w),
                          cvtpk2(bf2f(a1[2]) * w, bf2f(a1[3]) * w),
                          cvtpk2(bf2f(a1[4]) * w, bf2f(a1[5]) * w),
                          cvtpk2(bf2f(a1[6]) * w, bf2f(a1[7]) * w) };
        }
        *(uint4*)dst       = o0;
        *(uint4*)(dst + 8) = o1;
    }
}

// ---------------------------------------------------------------------------
// MFMA GEMM, 128x256 tile (BN=256 halves the dominant L3 A-panel re-fetch:
// A-traffic = (N/BN) x |A|), 8 waves as 2m x 4n (wave-tile 64x64, 4x4 acc),
// BK=32, 3-stage counted-vmcnt pipeline + 2-phase interleave. LDS 72 KB ->
// 2 blocks/CU, 16 waves/CU. B-panels (256 x K bf16, <=512 KB) are L2-resident
// and shared by 128 consecutive blocks (m-fastest grid).
// ---------------------------------------------------------------------------
template<int MODE>
__global__ __launch_bounds__(512) void gemm_mfma_bn_relu(
    const u16* __restrict__ A, const u16* __restrict__ W,
    const float* __restrict__ bias, const float* __restrict__ g,
    const float* __restrict__ be, u16* __restrict__ Cout,
    int M, int N, int Kp,
    const float* __restrict__ w_out, float* __restrict__ outp)
{
    // 3 stages x (A 4096 u16 + B 8192 u16) = 36864 u16 = 72 KB.
    // Epilogue reuses front 67584 B as the 128x264 C staging tile.
    __shared__ __align__(16) u16 SM[3 * 12288];

    const int t    = threadIdx.x;
    const int wave = t >> 6;
    const int lane = t & 63;
    const int wm   = wave >> 2, wn = wave & 3;   // 2 m-waves x 4 n-waves
    const int m0   = blockIdx.x * 128;
    const int n0   = blockIdx.y * 256;

    const int rA  = t >> 2;
    const int cA  = (t & 3) ^ ((rA >> 1) & 3);
    const int rB1 = 128 + rA;
    const int cB1 = (t & 3) ^ ((rB1 >> 1) & 3);
    const u16* gA  = A + (size_t)(m0 + rA)  * Kp + cA  * 8;
    const u16* gB0 = W + (size_t)(n0 + rA)  * Kp + cA  * 8;
    const u16* gB1 = W + (size_t)(n0 + rB1) * Kp + cB1 * 8;
    const int dA = t * 8, dB0 = 4096 + t * 8, dB1 = 8192 + t * 8;

    const int q    = lane >> 4;
    const int lr16 = lane & 15;

    int aoff[4], boff[4];
    #pragma unroll
    for (int i = 0; i < 4; ++i) {
        int ra = wm * 64 + i * 16 + lr16;
        aoff[i] = ra * 32 + ((q ^ ((ra >> 1) & 3)) * 8);
        int rb = wn * 64 + i * 16 + lr16;
        boff[i] = 4096 + rb * 32 + ((q ^ ((rb >> 1) & 3)) * 8);
    }

    const int NIT = Kp >> 5;     // 20 (GEMM0) / 32 (GEMM1)

    // prologue: stage k-blocks 0,1 into buffers 0,1  (6 GLDs outstanding)
    GLD16(gA,  SM + dA);
    GLD16(gB0, SM + dB0);
    GLD16(gB1, SM + dB1);
    gA += 32; gB0 += 32; gB1 += 32;
    GLD16(gA,  SM + 12288 + dA);
    GLD16(gB0, SM + 12288 + dB0);
    GLD16(gB1, SM + 12288 + dB1);
    gA += 32; gB0 += 32; gB1 += 32;

    f32x4 acc[4][4] = {};
    int cur = 0, stg = 2;

    for (int it = 0; it < NIT - 1; ++it) {
        asm volatile("s_waitcnt vmcnt(3)" ::: "memory");
        __builtin_amdgcn_s_barrier();
        __builtin_amdgcn_sched_barrier(0);

        const u16* ac = SM + cur * 12288;

        // phase 0: 6 ds_reads, GLD issue in their shadow, then 8 MFMA
        bf16x8 af0 = *(const bf16x8*)(ac + aoff[0]);
        bf16x8 af1 = *(const bf16x8*)(ac + aoff[1]);
        bf16x8 b0v = *(const bf16x8*)(ac + boff[0]);
        bf16x8 b1v = *(const bf16x8*)(ac + boff[1]);
        bf16x8 b2v = *(const bf16x8*)(ac + boff[2]);
        bf16x8 b3v = *(const bf16x8*)(ac + boff[3]);

        if (it + 2 < NIT) {
            u16* s = SM + stg * 12288;
            GLD16(gA,  s + dA);
            GLD16(gB0, s + dB0);
            GLD16(gB1, s + dB1);
            gA += 32; gB0 += 32; gB1 += 32;
        }

        asm volatile("s_waitcnt lgkmcnt(0)" ::: "memory");
        __builtin_amdgcn_sched_barrier(0);
        __builtin_amdgcn_s_setprio(1);
        acc[0][0] = __builtin_amdgcn_mfma_f32_16x16x32_bf16(af0, b0v, acc[0][0], 0, 0, 0);
        acc[0][1] = __builtin_amdgcn_mfma_f32_16x16x32_bf16(af0, b1v, acc[0][1], 0, 0, 0);
        acc[0][2] = __builtin_amdgcn_mfma_f32_16x16x32_bf16(af0, b2v, acc[0][2], 0, 0, 0);
        acc[0][3] = __builtin_amdgcn_mfma_f32_16x16x32_bf16(af0, b3v, acc[0][3], 0, 0, 0);
        acc[1][0] = __builtin_amdgcn_mfma_f32_16x16x32_bf16(af1, b0v, acc[1][0], 0, 0, 0);
        acc[1][1] = __builtin_amdgcn_mfma_f32_16x16x32_bf16(af1, b1v, acc[1][1], 0, 0, 0);
        acc[1][2] = __builtin_amdgcn_mfma_f32_16x16x32_bf16(af1, b2v, acc[1][2], 0, 0, 0);
        acc[1][3] = __builtin_amdgcn_mfma_f32_16x16x32_bf16(af1, b3v, acc[1][3], 0, 0, 0);
        __builtin_amdgcn_s_setprio(0);
        __builtin_amdgcn_s_barrier();     // phase alignment across waves

        // phase 1: 2 ds_reads, 8 MFMA
        bf16x8 af2 = *(const bf16x8*)(ac + aoff[2]);
        bf16x8 af3 = *(const bf16x8*)(ac + aoff[3]);
        asm volatile("s_waitcnt lgkmcnt(0)" ::: "memory");
        __builtin_amdgcn_sched_barrier(0);
        __builtin_amdgcn_s_setprio(1);
        acc[2][0] = __builtin_amdgcn_mfma_f32_16x16x32_bf16(af2, b0v, acc[2][0], 0, 0, 0);
        acc[2][1] = __builtin_amdgcn_mfma_f32_16x16x32_bf16(af2, b1v, acc[2][1], 0, 0, 0);
        acc[2][2] = __builtin_amdgcn_mfma_f32_16x16x32_bf16(af2, b2v, acc[2][2], 0, 0, 0);
        acc[2][3] = __builtin_amdgcn_mfma_f32_16x16x32_bf16(af2, b3v, acc[2][3], 0, 0, 0);
        acc[3][0] = __builtin_amdgcn_mfma_f32_16x16x32_bf16(af3, b0v, acc[3][0], 0, 0, 0);
        acc[3][1] = __builtin_amdgcn_mfma_f32_16x16x32_bf16(af3, b1v, acc[3][1], 0, 0, 0);
        acc[3][2] = __builtin_amdgcn_mfma_f32_16x16x32_bf16(af3, b2v, acc[3][2], 0, 0, 0);
        acc[3][3] = __builtin_amdgcn_mfma_f32_16x16x32_bf16(af3, b3v, acc[3][3], 0, 0, 0);
        __builtin_amdgcn_s_setprio(0);

        cur = (cur == 2) ? 0 : cur + 1;
        stg = (stg == 2) ? 0 : stg + 1;
    }

    // peeled final iteration: only 3 GLDs remain outstanding -> full drain
    asm volatile("s_waitcnt vmcnt(0)" ::: "memory");
    __builtin_amdgcn_s_barrier();
    __builtin_amdgcn_sched_barrier(0);
    {
        const u16* ac = SM + cur * 12288;
        bf16x8 af[4], bfr[4];
        #pragma unroll
        for (int i = 0; i < 4; ++i) af[i]  = *(const bf16x8*)(ac + aoff[i]);
        #pragma unroll
        for (int j = 0; j < 4; ++j) bfr[j] = *(const bf16x8*)(ac + boff[j]);
        __builtin_amdgcn_s_setprio(1);
        #pragma unroll
        for (int i = 0; i < 4; ++i)
            #pragma unroll
            for (int j = 0; j < 4; ++j)
                acc[i][j] = __builtin_amdgcn_mfma_f32_16x16x32_bf16(
                    af[i], bfr[j], acc[i][j], 0, 0, 0);
        __builtin_amdgcn_s_setprio(0);
    }

    const float rs = rsqrtf(1.0f + 1e-5f);
    if (MODE == 0) {
        // stage C tile in LDS (128 x 264 u16), packed converts, then
        // 16B/lane coalesced stores.
        __syncthreads();            // all waves done reading SM
        u16* Cs = SM;               // 128*264*2 = 67584 B <= 73728
        #pragma unroll
        for (int j = 0; j < 4; ++j) {
            const int nl = wn * 64 + j * 16 + lr16;
            const int n  = n0 + nl;
            const float bn_g = g[n] * rs;
            const float bn_b = be[n];
            const float bi   = bias[n];
            #pragma unroll
            for (int i = 0; i < 4; ++i) {
                const int mlb = wm * 64 + i * 16 + q * 4;
                float v0 = fmaxf(fmaf(bn_g, acc[i][j][0] + bi, bn_b), 0.f);
                float v1 = fmaxf(fmaf(bn_g, acc[i][j][1] + bi, bn_b), 0.f);
                float v2 = fmaxf(fmaf(bn_g, acc[i][j][2] + bi, bn_b), 0.f);
                float v3 = fmaxf(fmaf(bn_g, acc[i][j][3] + bi, bn_b), 0.f);
                unsigned pA = cvtpk2(v0, v1);
                unsigned pB = cvtpk2(v2, v3);
                Cs[(mlb + 0) * 264 + nl] = (u16)pA;
                Cs[(mlb + 1) * 264 + nl] = (u16)(pA >> 16);
                Cs[(mlb + 2) * 264 + nl] = (u16)pB;
                Cs[(mlb + 3) * 264 + nl] = (u16)(pB >> 16);
            }
        }
        __syncthreads();
        #pragma unroll
        for (int s = 0; s < 8; ++s) {
            const int chunk = s * 512 + t;      // 0..4095
            const int row   = chunk >> 5;       // 128 rows
            const int col   = (chunk & 31) << 3;
            *(u16x8*)&Cout[(size_t)(m0 + row) * N + n0 + col] =
                *(const u16x8*)&Cs[row * 264 + col];
        }
    } else {
        float s[4][4] = {};
        #pragma unroll
        for (int j = 0; j < 4; ++j) {
            const int n = n0 + wn * 64 + j * 16 + lr16;
            const float bn_g = g[n] * rs;
            const float bn_b = be[n];
            const float bi   = bias[n];
            const float wo   = w_out[n];
            #pragma unroll
            for (int i = 0; i < 4; ++i)
                #pragma unroll
                for (int r = 0; r < 4; ++r) {
                    float v = acc[i][j][r] + bi;
                    v = fmaxf(fmaf(bn_g, v, bn_b), 0.f);
                    s[i][r] = fmaf(v, wo, s[i][r]);
                }
        }
        #pragma unroll
        for (int i = 0; i < 4; ++i)
            #pragma unroll
            for (int r = 0; r < 4; ++r) {
                float v = s[i][r];
                v += __shfl_xor(v, 1, 64);
                v += __shfl_xor(v, 2, 64);
                v += __shfl_xor(v, 4, 64);
                v += __shfl_xor(v, 8, 64);
                s[i][r] = v;
            }
        if (lr16 == 0) {
            #pragma unroll
            for (int i = 0; i < 4; ++i) {
                const int mbase = m0 + wm * 64 + i * 16 + q * 4;
                #pragma unroll
                for (int r = 0; r < 4; ++r)
                    atomicAdd(&outp[mbase + r], s[i][r]);
            }
        }
    }
}

// ---------------------------------------------------------------------------
// out[b] = sigmoid(outp[b] + b_out)
// ---------------------------------------------------------------------------
__global__ __launch_bounds__(256) void sigmoid_kernel(
    const float* __restrict__ outp, const float* __restrict__ b_out,
    float* __restrict__ out)
{
    const int b = blockIdx.x * 256 + threadIdx.x;
    out[b] = 1.f / (1.f + expf(-(outp[b] + b_out[0])));
}

// ---------------------------------------------------------------------------
extern "C" void kernel_launch(void* const* d_in, const int* in_sizes, int n_in,
                              void* d_out, int out_size, void* d_ws, size_t ws_size,
                              hipStream_t stream)
{
    const int*   x     = (const int*)  d_in[0];
    const float* emb   = (const float*)d_in[1];
    const float* w_c   = (const float*)d_in[2];
    const float* b_c   = (const float*)d_in[3];
    const float* g_c   = (const float*)d_in[4];
    const float* be_c  = (const float*)d_in[5];
    const float* w0    = (const float*)d_in[6];
    const float* b0    = (const float*)d_in[7];
    const float* g0    = (const float*)d_in[8];
    const float* be0   = (const float*)d_in[9];
    const float* w1    = (const float*)d_in[10];
    const float* b1    = (const float*)d_in[11];
    const float* g1    = (const float*)d_in[12];
    const float* be1   = (const float*)d_in[13];
    const float* w_out = (const float*)d_in[14];
    const float* b_out = (const float*)d_in[15];
    float* out = (float*)d_out;

    // workspace layout (~57 MB)
    u16*   zb    = (u16*)d_ws;                          // B*640*2  = 20.97 MB
    u16*   w0b   = zb    + (size_t)B_SZ * KP0;          // 1.31 MB
    u16*   h0b   = w0b   + (size_t)N0 * KP0;            // 33.55 MB
    u16*   w1b   = h0b   + (size_t)B_SZ * N0;           // 1.05 MB
    u16*   wcb   = w1b   + (size_t)N1 * N0;             // 0.06 MB
    float* outp  = (float*)(wcb + (size_t)NCP * KP0);   // 64 KB
    float* bcp   = outp + B_SZ;
    float* gcp   = bcp + NCP;
    float* becp  = gcp + NCP;

    prep_all_kernel<<<399, 256, 0, stream>>>(
        w0, w1, w_c, b_c, g_c, be_c, w0b, w1b, wcb, bcp, gcp, becp, outp);

    fused_controller_kernel<<<B_SZ / CBR, 256, 0, stream>>>(
        x, emb, wcb, bcp, gcp, becp, zb);

    gemm_mfma_bn_relu<0><<<dim3(B_SZ / 128, N0 / 256), 512, 0, stream>>>(
        zb, w0b, b0, g0, be0, h0b, B_SZ, N0, KP0, nullptr, nullptr);

    gemm_mfma_bn_relu<1><<<dim3(B_SZ / 128, N1 / 256), 512, 0, stream>>>(
        h0b, w1b, b1, g1, be1, nullptr, B_SZ, N1, N0, w_out, outp);

    sigmoid_kernel<<<B_SZ / 256, 256, 0, stream>>>(outp, b_out, out);
}

// Round 5
// 219.215 us; speedup vs baseline: 1.0179x; 1.0179x over previous
//
#include <hip/hip_runtime.h>
#include <math.h>

#define B_SZ 16384
#define F_N 39
#define V_N 30000
#define D_N 16
#define K_SEL 20
#define FD 624     // F_N * D_N
#define KP0 640    // controller/GEMM0 K padded to multiple of 32
#define NCP 48     // controller GEMM padded N (>= 39, 3 n-tiles of 16)
#define N0 1024
#define N1 512
#define CBR 16     // batch rows per fused-controller block
#define ALD 648    // LDS row stride (u16)

typedef unsigned short u16;
typedef __attribute__((ext_vector_type(8))) short bf16x8;
typedef __attribute__((ext_vector_type(8))) unsigned short u16x8;
typedef __attribute__((ext_vector_type(4))) float f32x4;

__device__ __forceinline__ u16 f2bf(float v) {
    union { float f; unsigned u; } x; x.f = v;
    unsigned r = x.u + 0x7fff + ((x.u >> 16) & 1);   // RNE
    return (u16)(r >> 16);
}
__device__ __forceinline__ float bf2f(u16 v) {
    union { unsigned u; float f; } x; x.u = ((unsigned)v) << 16;
    return x.f;
}
// HW packed convert: D[15:0]=bf16(a), D[31:16]=bf16(b), RNE.
__device__ __forceinline__ unsigned cvtpk2(float a, float b) {
    unsigned d;
    asm("v_cvt_pk_bf16_f32 %0, %1, %2" : "=v"(d) : "v"(a), "v"(b));
    return d;
}

#define GLD16(gp, lp) __builtin_amdgcn_global_load_lds( \
    (const __attribute__((address_space(1))) unsigned int*)(gp), \
    (__attribute__((address_space(3))) unsigned int*)(lp), 16, 0, 0)

// ---------------------------------------------------------------------------
// prep (coalesced): segment by blockIdx.
// ---------------------------------------------------------------------------
__global__ __launch_bounds__(256) void prep_all_kernel(
    const float* __restrict__ w0, const float* __restrict__ w1,
    const float* __restrict__ w_c, const float* __restrict__ b_c,
    const float* __restrict__ g_c, const float* __restrict__ be_c,
    u16* __restrict__ w0b, u16* __restrict__ w1b, u16* __restrict__ wcb,
    float* __restrict__ bcp, float* __restrict__ gcp, float* __restrict__ becp,
    float* __restrict__ outp)
{
    __shared__ float Lb[8][624];
    const int bid = blockIdx.x;
    const int t   = threadIdx.x;

    if (bid < 134) {                       // w0 (bid<128) or wc permute
        const bool is_w0 = (bid < 128);
        const int r0 = is_w0 ? bid * 8 : (bid - 128) * 8;
        const int nrows_src = is_w0 ? N0 : F_N;
        const float* __restrict__ src = is_w0 ? w0 : w_c;
        u16* __restrict__ dst = is_w0 ? w0b : wcb;

        for (int j = t; j < 8 * 156; j += 256) {
            const int row = j / 156;
            const int c4  = j - row * 156;
            const int n   = r0 + row;
            if (n < nrows_src)
                *(float4*)&Lb[row][c4 * 4] =
                    *(const float4*)&src[(size_t)n * FD + c4 * 4];
        }
        __syncthreads();

        for (int j = t; j < 8 * 320; j += 256) {
            const int row = j / 320;
            const int pr  = j - row * 320;
            const int n   = r0 + row;
            const int k0  = pr * 2;
            float v0 = 0.f, v1 = 0.f;
            if (n < nrows_src) {
                const int d0 = k0 & 15,       f0 = k0 >> 4;
                const int d1 = (k0 + 1) & 15, f1 = (k0 + 1) >> 4;
                if (f0 < F_N) v0 = Lb[row][d0 * F_N + f0];
                if (f1 < F_N) v1 = Lb[row][d1 * F_N + f1];
            }
            *(unsigned*)&dst[(size_t)n * KP0 + k0] = cvtpk2(v0, v1);
        }
        return;
    }
    if (bid < 390) {                       // w1 convert
        const size_t e0 = (size_t)(bid - 134) * 2048 + t * 8;
        float4 v0 = *(const float4*)(w1 + e0);
        float4 v1 = *(const float4*)(w1 + e0 + 4);
        uint4 o = { cvtpk2(v0.x, v0.y), cvtpk2(v0.z, v0.w),
                    cvtpk2(v1.x, v1.y), cvtpk2(v1.z, v1.w) };
        *(uint4*)(w1b + e0) = o;
        return;
    }
    if (bid < 398) {                       // outp zero
        const size_t e0 = (size_t)(bid - 390) * 2048 + t * 8;
        float4 z = {0.f, 0.f, 0.f, 0.f};
        *(float4*)(outp + e0)     = z;
        *(float4*)(outp + e0 + 4) = z;
        return;
    }
    if (t < 3 * NCP) {
        const int which = t / NCP, n = t - which * NCP;
        float v = 0.f;
        if (n < F_N) v = (which == 0) ? b_c[n] : (which == 1) ? g_c[n] : be_c[n];
        ((which == 0) ? bcp : (which == 1) ? gcp : becp)[n] = v;
    }
}

// ---------------------------------------------------------------------------
// Dedicated gather: 1 thread = 1 (b,f) row. Random 64B read, cvt_pk, 32B
// coalesced store to dense gb[B,640]. No LDS, low VGPR -> 32 waves/CU of
// latency hiding (the resource round-4's fused gather lacked).
// Grid covers exactly B*F threads (16384*39/256 = 2496 blocks).
// ---------------------------------------------------------------------------
__global__ __launch_bounds__(256) void gather_kernel(
    const int* __restrict__ x, const float* __restrict__ emb_table,
    u16* __restrict__ gb)
{
    const int p = blockIdx.x * 256 + threadIdx.x;   // 0 .. B*F-1
    const int b = p / F_N;
    const int f = p - b * F_N;
    const int xi = x[p];
    const float4* src = (const float4*)(emb_table + (size_t)(xi + f * V_N) * D_N);
    float4 v0 = src[0], v1 = src[1], v2 = src[2], v3 = src[3];
    uint4 o0 = { cvtpk2(v0.x, v0.y), cvtpk2(v0.z, v0.w),
                 cvtpk2(v1.x, v1.y), cvtpk2(v1.z, v1.w) };
    uint4 o1 = { cvtpk2(v2.x, v2.y), cvtpk2(v2.z, v2.w),
                 cvtpk2(v3.x, v3.y), cvtpk2(v3.z, v3.w) };
    u16* dst = gb + (size_t)b * KP0 + f * D_N;
    *(uint4*)dst       = o0;
    *(uint4*)(dst + 8) = o1;
}

// ---------------------------------------------------------------------------
// Fused controller (CBR=16, 4 waves, ~39KB LDS -> 4 blocks/CU): coalesced
// gb->LDS stage (L3-hit), 16x48 MFMA split-K, all-wave reduce, wave-sliced
// bn/softmax/top-K rank, select-scale -> zb. Pad k in [624,640) staged as
// zeros explicitly.
// ---------------------------------------------------------------------------
__global__ __launch_bounds__(256) void fused_controller_kernel(
    const u16* __restrict__ gb, const u16* __restrict__ wcb,
    const float* __restrict__ bcp, const float* __restrict__ gcp,
    const float* __restrict__ becp, u16* __restrict__ zb)
{
    __shared__ __align__(16) u16 Al[CBR * ALD];
    __shared__ float vv[CBR][49];
    __shared__ f32x4 part[4][64][3];
    __shared__ float selw[CBR][F_N];

    const int t    = threadIdx.x;
    const int wave = t >> 6;
    const int lane = t & 63;
    const int b0   = blockIdx.x * CBR;

    // ---- stage: 16 rows x 80 u16x8-chunks from gb (coalesced, L3-hit) ----
    #pragma unroll
    for (int s = 0; s < 5; ++s) {
        const int j   = t + s * 256;          // 0..1279
        const int row = j / 80;
        const int c   = j - row * 80;
        uint4 v = {0u, 0u, 0u, 0u};
        if (c < 78)                           // k < 624; chunks 78,79 = pad 0
            v = *(const uint4*)&gb[(size_t)(b0 + row) * KP0 + c * 8];
        *(uint4*)&Al[row * ALD + c * 8] = v;
    }
    __syncthreads();

    const int m = lane & 15;
    const int q = lane >> 4;
    f32x4 acc0 = {}, acc1 = {}, acc2 = {};
    {
        const u16* ap  = &Al[m * ALD + wave * 160 + q * 8];
        const u16* bp0 = wcb + (size_t)(0  + m) * KP0 + wave * 160 + q * 8;
        const u16* bp1 = wcb + (size_t)(16 + m) * KP0 + wave * 160 + q * 8;
        const u16* bp2 = wcb + (size_t)(32 + m) * KP0 + wave * 160 + q * 8;
        #pragma unroll
        for (int k = 0; k < 5; ++k) {
            bf16x8 af = *(const bf16x8*)ap;
            bf16x8 b0 = *(const bf16x8*)bp0;
            bf16x8 b1 = *(const bf16x8*)bp1;
            bf16x8 b2 = *(const bf16x8*)bp2;
            acc0 = __builtin_amdgcn_mfma_f32_16x16x32_bf16(af, b0, acc0, 0, 0, 0);
            acc1 = __builtin_amdgcn_mfma_f32_16x16x32_bf16(af, b1, acc1, 0, 0, 0);
            acc2 = __builtin_amdgcn_mfma_f32_16x16x32_bf16(af, b2, acc2, 0, 0, 0);
            ap += 32; bp0 += 32; bp1 += 32; bp2 += 32;
        }
    }
    part[wave][lane][0] = acc0;
    part[wave][lane][1] = acc1;
    part[wave][lane][2] = acc2;
    __syncthreads();

    {
        f32x4 r0 = part[0][lane][0] + part[1][lane][0] + part[2][lane][0] + part[3][lane][0];
        f32x4 r1 = part[0][lane][1] + part[1][lane][1] + part[2][lane][1] + part[3][lane][1];
        f32x4 r2 = part[0][lane][2] + part[1][lane][2] + part[2][lane][2] + part[3][lane][2];

        const float rs = rsqrtf(1.0f + 1e-5f);
        if (q == wave) {
            #pragma unroll
            for (int j = 0; j < 3; ++j) {
                const f32x4 a = (j == 0) ? r0 : (j == 1) ? r1 : r2;
                const int n = j * 16 + m;
                const float gn = gcp[n] * rs;
                const float bn = becp[n];
                const float bi = bcp[n];
                #pragma unroll
                for (int r = 0; r < 4; ++r)
                    vv[wave * 4 + r][n] = fmaxf(fmaf(gn, a[r] + bi, bn), 0.f);
            }
        }
    }
    __syncthreads();

    {
        const int row = wave * 4 + (lane >> 4);
        const int fl  = lane & 15;
        float e[3] = {0.f, 0.f, 0.f};
        float mloc = -1e30f;
        #pragma unroll
        for (int it = 0; it < 3; ++it) {
            const int f = fl + 16 * it;
            if (f < F_N) { e[it] = vv[row][f]; mloc = fmaxf(mloc, e[it]); }
        }
        mloc = fmaxf(mloc, __shfl_xor(mloc, 1, 64));
        mloc = fmaxf(mloc, __shfl_xor(mloc, 2, 64));
        mloc = fmaxf(mloc, __shfl_xor(mloc, 4, 64));
        mloc = fmaxf(mloc, __shfl_xor(mloc, 8, 64));
        float sloc = 0.f;
        #pragma unroll
        for (int it = 0; it < 3; ++it) {
            const int f = fl + 16 * it;
            if (f < F_N) { e[it] = expf(e[it] - mloc); sloc += e[it]; }
        }
        sloc += __shfl_xor(sloc, 1, 64);
        sloc += __shfl_xor(sloc, 2, 64);
        sloc += __shfl_xor(sloc, 4, 64);
        sloc += __shfl_xor(sloc, 8, 64);
        const float inv = 1.f / sloc;
        #pragma unroll
        for (int it = 0; it < 3; ++it) {
            const int f = fl + 16 * it;
            if (f < F_N) vv[row][f] = e[it];
        }

        int rank[3] = {};
        for (int gg = 0; gg < F_N; ++gg) {
            const float o = vv[row][gg];
            #pragma unroll
            for (int it = 0; it < 3; ++it) {
                const int f = fl + 16 * it;
                if (f < F_N)
                    rank[it] += (o > e[it] || (o == e[it] && gg < f)) ? 1 : 0;
            }
        }
        #pragma unroll
        for (int it = 0; it < 3; ++it) {
            const int f = fl + 16 * it;
            if (f < F_N)
                selw[row][f] = (rank[it] < K_SEL) ? e[it] * inv : 0.f;
        }
    }
    __syncthreads();

    // zb write: row-major work mapping, packed converts, coalesced.
    for (int gp = t; gp < CBR * 40; gp += 256) {
        const int row  = gp / 40;
        const int slot = gp - row * 40;
        u16* dst = zb + (size_t)(b0 + row) * KP0 + slot * D_N;
        uint4 o0 = {0u,0u,0u,0u}, o1 = {0u,0u,0u,0u};
        if (slot < F_N) {
            const float w = selw[row][slot];
            u16x8 a0 = *(u16x8*)&Al[row * ALD + slot * D_N];
            u16x8 a1 = *(u16x8*)&Al[row * ALD + slot * D_N + 8];
            o0 = (uint4){ cvtpk2(bf2f(a0[0]) * w, bf2f(a0[1]) * w),
                          cvtpk2(bf2f(a0[2]) * w, bf2f(a0[3]) * w),
                          cvtpk2(bf2f(a0[4]) * w, bf2f(a0[5]) * w),
                          cvtpk2(bf2f(a0[6]) * w, bf2f(a0[7]) * w) };
            o1 = (uint4){ cvtpk2(bf2f(a1[0]) * w, bf2f(a1[1]) * w),
                          cvtpk2(bf2f(a1[2]) * w, bf2f(a1[3]) * w),
                          cvtpk2(bf2f(a1[4]) * w, bf2f(a1[5]) * w),
                          cvtpk2(bf2f(a1[6]) * w, bf2f(a1[7]) * w) };
        }
        *(uint4*)dst       = o0;
        *(uint4*)(dst + 8) = o1;
    }
}

// ---------------------------------------------------------------------------
// MFMA GEMM, 128x256 tile, 8 waves as 2m x 4n, BK=32, 3-stage counted-vmcnt
// pipeline + 2-phase interleave (unchanged from round 3 proposal).
// ---------------------------------------------------------------------------
template<int MODE>
__global__ __launch_bounds__(512) void gemm_mfma_bn_relu(
    const u16* __restrict__ A, const u16* __restrict__ W,
    const float* __restrict__ bias, const float* __restrict__ g,
    const float* __restrict__ be, u16* __restrict__ Cout,
    int M, int N, int Kp,
    const float* __restrict__ w_out, float* __restrict__ outp)
{
    __shared__ __align__(16) u16 SM[3 * 12288];

    const int t    = threadIdx.x;
    const int wave = t >> 6;
    const int lane = t & 63;
    const int wm   = wave >> 2, wn = wave & 3;   // 2 m-waves x 4 n-waves
    const int m0   = blockIdx.x * 128;
    const int n0   = blockIdx.y * 256;

    const int rA  = t >> 2;
    const int cA  = (t & 3) ^ ((rA >> 1) & 3);
    const int rB1 = 128 + rA;
    const int cB1 = (t & 3) ^ ((rB1 >> 1) & 3);
    const u16* gA  = A + (size_t)(m0 + rA)  * Kp + cA  * 8;
    const u16* gB0 = W + (size_t)(n0 + rA)  * Kp + cA  * 8;
    const u16* gB1 = W + (size_t)(n0 + rB1) * Kp + cB1 * 8;
    const int dA = t * 8, dB0 = 4096 + t * 8, dB1 = 8192 + t * 8;

    const int q    = lane >> 4;
    const int lr16 = lane & 15;

    int aoff[4], boff[4];
    #pragma unroll
    for (int i = 0; i < 4; ++i) {
        int ra = wm * 64 + i * 16 + lr16;
        aoff[i] = ra * 32 + ((q ^ ((ra >> 1) & 3)) * 8);
        int rb = wn * 64 + i * 16 + lr16;
        boff[i] = 4096 + rb * 32 + ((q ^ ((rb >> 1) & 3)) * 8);
    }

    const int NIT = Kp >> 5;     // 20 (GEMM0) / 32 (GEMM1)

    GLD16(gA,  SM + dA);
    GLD16(gB0, SM + dB0);
    GLD16(gB1, SM + dB1);
    gA += 32; gB0 += 32; gB1 += 32;
    GLD16(gA,  SM + 12288 + dA);
    GLD16(gB0, SM + 12288 + dB0);
    GLD16(gB1, SM + 12288 + dB1);
    gA += 32; gB0 += 32; gB1 += 32;

    f32x4 acc[4][4] = {};
    int cur = 0, stg = 2;

    for (int it = 0; it < NIT - 1; ++it) {
        asm volatile("s_waitcnt vmcnt(3)" ::: "memory");
        __builtin_amdgcn_s_barrier();
        __builtin_amdgcn_sched_barrier(0);

        const u16* ac = SM + cur * 12288;

        bf16x8 af0 = *(const bf16x8*)(ac + aoff[0]);
        bf16x8 af1 = *(const bf16x8*)(ac + aoff[1]);
        bf16x8 b0v = *(const bf16x8*)(ac + boff[0]);
        bf16x8 b1v = *(const bf16x8*)(ac + boff[1]);
        bf16x8 b2v = *(const bf16x8*)(ac + boff[2]);
        bf16x8 b3v = *(const bf16x8*)(ac + boff[3]);

        if (it + 2 < NIT) {
            u16* s = SM + stg * 12288;
            GLD16(gA,  s + dA);
            GLD16(gB0, s + dB0);
            GLD16(gB1, s + dB1);
            gA += 32; gB0 += 32; gB1 += 32;
        }

        asm volatile("s_waitcnt lgkmcnt(0)" ::: "memory");
        __builtin_amdgcn_sched_barrier(0);
        __builtin_amdgcn_s_setprio(1);
        acc[0][0] = __builtin_amdgcn_mfma_f32_16x16x32_bf16(af0, b0v, acc[0][0], 0, 0, 0);
        acc[0][1] = __builtin_amdgcn_mfma_f32_16x16x32_bf16(af0, b1v, acc[0][1], 0, 0, 0);
        acc[0][2] = __builtin_amdgcn_mfma_f32_16x16x32_bf16(af0, b2v, acc[0][2], 0, 0, 0);
        acc[0][3] = __builtin_amdgcn_mfma_f32_16x16x32_bf16(af0, b3v, acc[0][3], 0, 0, 0);
        acc[1][0] = __builtin_amdgcn_mfma_f32_16x16x32_bf16(af1, b0v, acc[1][0], 0, 0, 0);
        acc[1][1] = __builtin_amdgcn_mfma_f32_16x16x32_bf16(af1, b1v, acc[1][1], 0, 0, 0);
        acc[1][2] = __builtin_amdgcn_mfma_f32_16x16x32_bf16(af1, b2v, acc[1][2], 0, 0, 0);
        acc[1][3] = __builtin_amdgcn_mfma_f32_16x16x32_bf16(af1, b3v, acc[1][3], 0, 0, 0);
        __builtin_amdgcn_s_setprio(0);
        __builtin_amdgcn_s_barrier();

        bf16x8 af2 = *(const bf16x8*)(ac + aoff[2]);
        bf16x8 af3 = *(const bf16x8*)(ac + aoff[3]);
        asm volatile("s_waitcnt lgkmcnt(0)" ::: "memory");
        __builtin_amdgcn_sched_barrier(0);
        __builtin_amdgcn_s_setprio(1);
        acc[2][0] = __builtin_amdgcn_mfma_f32_16x16x32_bf16(af2, b0v, acc[2][0], 0, 0, 0);
        acc[2][1] = __builtin_amdgcn_mfma_f32_16x16x32_bf16(af2, b1v, acc[2][1], 0, 0, 0);
        acc[2][2] = __builtin_amdgcn_mfma_f32_16x16x32_bf16(af2, b2v, acc[2][2], 0, 0, 0);
        acc[2][3] = __builtin_amdgcn_mfma_f32_16x16x32_bf16(af2, b3v, acc[2][3], 0, 0, 0);
        acc[3][0] = __builtin_amdgcn_mfma_f32_16x16x32_bf16(af3, b0v, acc[3][0], 0, 0, 0);
        acc[3][1] = __builtin_amdgcn_mfma_f32_16x16x32_bf16(af3, b1v, acc[3][1], 0, 0, 0);
        acc[3][2] = __builtin_amdgcn_mfma_f32_16x16x32_bf16(af3, b2v, acc[3][2], 0, 0, 0);
        acc[3][3] = __builtin_amdgcn_mfma_f32_16x16x32_bf16(af3, b3v, acc[3][3], 0, 0, 0);
        __builtin_amdgcn_s_setprio(0);

        cur = (cur == 2) ? 0 : cur + 1;
        stg = (stg == 2) ? 0 : stg + 1;
    }

    asm volatile("s_waitcnt vmcnt(0)" ::: "memory");
    __builtin_amdgcn_s_barrier();
    __builtin_amdgcn_sched_barrier(0);
    {
        const u16* ac = SM + cur * 12288;
        bf16x8 af[4], bfr[4];
        #pragma unroll
        for (int i = 0; i < 4; ++i) af[i]  = *(const bf16x8*)(ac + aoff[i]);
        #pragma unroll
        for (int j = 0; j < 4; ++j) bfr[j] = *(const bf16x8*)(ac + boff[j]);
        __builtin_amdgcn_s_setprio(1);
        #pragma unroll
        for (int i = 0; i < 4; ++i)
            #pragma unroll
            for (int j = 0; j < 4; ++j)
                acc[i][j] = __builtin_amdgcn_mfma_f32_16x16x32_bf16(
                    af[i], bfr[j], acc[i][j], 0, 0, 0);
        __builtin_amdgcn_s_setprio(0);
    }

    const float rs = rsqrtf(1.0f + 1e-5f);
    if (MODE == 0) {
        __syncthreads();
        u16* Cs = SM;               // 128*264*2 = 67584 B
        #pragma unroll
        for (int j = 0; j < 4; ++j) {
            const int nl = wn * 64 + j * 16 + lr16;
            const int n  = n0 + nl;
            const float bn_g = g[n] * rs;
            const float bn_b = be[n];
            const float bi   = bias[n];
            #pragma unroll
            for (int i = 0; i < 4; ++i) {
                const int mlb = wm * 64 + i * 16 + q * 4;
                float v0 = fmaxf(fmaf(bn_g, acc[i][j][0] + bi, bn_b), 0.f);
                float v1 = fmaxf(fmaf(bn_g, acc[i][j][1] + bi, bn_b), 0.f);
                float v2 = fmaxf(fmaf(bn_g, acc[i][j][2] + bi, bn_b), 0.f);
                float v3 = fmaxf(fmaf(bn_g, acc[i][j][3] + bi, bn_b), 0.f);
                unsigned pA = cvtpk2(v0, v1);
                unsigned pB = cvtpk2(v2, v3);
                Cs[(mlb + 0) * 264 + nl] = (u16)pA;
                Cs[(mlb + 1) * 264 + nl] = (u16)(pA >> 16);
                Cs[(mlb + 2) * 264 + nl] = (u16)pB;
                Cs[(mlb + 3) * 264 + nl] = (u16)(pB >> 16);
            }
        }
        __syncthreads();
        #pragma unroll
        for (int s = 0; s < 8; ++s) {
            const int chunk = s * 512 + t;      // 0..4095
            const int row   = chunk >> 5;       // 128 rows
            const int col   = (chunk & 31) << 3;
            *(u16x8*)&Cout[(size_t)(m0 + row) * N + n0 + col] =
                *(const u16x8*)&Cs[row * 264 + col];
        }
    } else {
        float s[4][4] = {};
        #pragma unroll
        for (int j = 0; j < 4; ++j) {
            const int n = n0 + wn * 64 + j * 16 + lr16;
            const float bn_g = g[n] * rs;
            const float bn_b = be[n];
            const float bi   = bias[n];
            const float wo   = w_out[n];
            #pragma unroll
            for (int i = 0; i < 4; ++i)
                #pragma unroll
                for (int r = 0; r < 4; ++r) {
                    float v = acc[i][j][r] + bi;
                    v = fmaxf(fmaf(bn_g, v, bn_b), 0.f);
                    s[i][r] = fmaf(v, wo, s[i][r]);
                }
        }
        #pragma unroll
        for (int i = 0; i < 4; ++i)
            #pragma unroll
            for (int r = 0; r < 4; ++r) {
                float v = s[i][r];
                v += __shfl_xor(v, 1, 64);
                v += __shfl_xor(v, 2, 64);
                v += __shfl_xor(v, 4, 64);
                v += __shfl_xor(v, 8, 64);
                s[i][r] = v;
            }
        if (lr16 == 0) {
            #pragma unroll
            for (int i = 0; i < 4; ++i) {
                const int mbase = m0 + wm * 64 + i * 16 + q * 4;
                #pragma unroll
                for (int r = 0; r < 4; ++r)
                    atomicAdd(&outp[mbase + r], s[i][r]);
            }
        }
    }
}

// ---------------------------------------------------------------------------
// out[b] = sigmoid(outp[b] + b_out)
// ---------------------------------------------------------------------------
__global__ __launch_bounds__(256) void sigmoid_kernel(
    const float* __restrict__ outp, const float* __restrict__ b_out,
    float* __restrict__ out)
{
    const int b = blockIdx.x * 256 + threadIdx.x;
    out[b] = 1.f / (1.f + expf(-(outp[b] + b_out[0])));
}

// ---------------------------------------------------------------------------
extern "C" void kernel_launch(void* const* d_in, const int* in_sizes, int n_in,
                              void* d_out, int out_size, void* d_ws, size_t ws_size,
                              hipStream_t stream)
{
    const int*   x     = (const int*)  d_in[0];
    const float* emb   = (const float*)d_in[1];
    const float* w_c   = (const float*)d_in[2];
    const float* b_c   = (const float*)d_in[3];
    const float* g_c   = (const float*)d_in[4];
    const float* be_c  = (const float*)d_in[5];
    const float* w0    = (const float*)d_in[6];
    const float* b0    = (const float*)d_in[7];
    const float* g0    = (const float*)d_in[8];
    const float* be0   = (const float*)d_in[9];
    const float* w1    = (const float*)d_in[10];
    const float* b1    = (const float*)d_in[11];
    const float* g1    = (const float*)d_in[12];
    const float* be1   = (const float*)d_in[13];
    const float* w_out = (const float*)d_in[14];
    const float* b_out = (const float*)d_in[15];
    float* out = (float*)d_out;

    // workspace layout (~78 MB; ws is ~300 MB per poison-fill size)
    u16*   zb    = (u16*)d_ws;                          // B*640*2  = 20.97 MB
    u16*   w0b   = zb    + (size_t)B_SZ * KP0;          // 1.31 MB
    u16*   h0b   = w0b   + (size_t)N0 * KP0;            // 33.55 MB
    u16*   w1b   = h0b   + (size_t)B_SZ * N0;           // 1.05 MB
    u16*   wcb   = w1b   + (size_t)N1 * N0;             // 0.06 MB
    float* outp  = (float*)(wcb + (size_t)NCP * KP0);   // 64 KB
    float* bcp   = outp + B_SZ;
    float* gcp   = bcp + NCP;
    float* becp  = gcp + NCP;
    u16*   gb    = (u16*)(becp + NCP);                  // B*640*2 = 20.97 MB

    prep_all_kernel<<<399, 256, 0, stream>>>(
        w0, w1, w_c, b_c, g_c, be_c, w0b, w1b, wcb, bcp, gcp, becp, outp);

    gather_kernel<<<(B_SZ * F_N) / 256, 256, 0, stream>>>(x, emb, gb);

    fused_controller_kernel<<<B_SZ / CBR, 256, 0, stream>>>(
        gb, wcb, bcp, gcp, becp, zb);

    gemm_mfma_bn_relu<0><<<dim3(B_SZ / 128, N0 / 256), 512, 0, stream>>>(
        zb, w0b, b0, g0, be0, h0b, B_SZ, N0, KP0, nullptr, nullptr);

    gemm_mfma_bn_relu<1><<<dim3(B_SZ / 128, N1 / 256), 512, 0, stream>>>(
        h0b, w1b, b1, g1, be1, nullptr, B_SZ, N1, N0, w_out, outp);

    sigmoid_kernel<<<B_SZ / 256, 256, 0, stream>>>(outp, b_out, out);
}

// Round 6
// 204.904 us; speedup vs baseline: 1.0890x; 1.0698x over previous
//
#include <hip/hip_runtime.h>
#include <math.h>

#define B_SZ 16384
#define F_N 39
#define V_N 30000
#define D_N 16
#define K_SEL 20
#define FD 624     // F_N * D_N
#define KP0 640    // controller/GEMM0 K padded to multiple of 32
#define NCP 48     // controller GEMM padded N (>= 39, 3 n-tiles of 16)
#define N0 1024
#define N1 512
#define CBR 16     // batch rows per fused-controller block
#define ALD 648    // LDS row stride (u16)

typedef unsigned short u16;
typedef __attribute__((ext_vector_type(8))) short bf16x8;
typedef __attribute__((ext_vector_type(8))) unsigned short u16x8;
typedef __attribute__((ext_vector_type(4))) float f32x4;

__device__ __forceinline__ u16 f2bf(float v) {
    union { float f; unsigned u; } x; x.f = v;
    unsigned r = x.u + 0x7fff + ((x.u >> 16) & 1);   // RNE
    return (u16)(r >> 16);
}
__device__ __forceinline__ float bf2f(u16 v) {
    union { unsigned u; float f; } x; x.u = ((unsigned)v) << 16;
    return x.f;
}
// HW packed convert: D[15:0]=bf16(a), D[31:16]=bf16(b), RNE.
__device__ __forceinline__ unsigned cvtpk2(float a, float b) {
    unsigned d;
    asm("v_cvt_pk_bf16_f32 %0, %1, %2" : "=v"(d) : "v"(a), "v"(b));
    return d;
}

#define GLD16(gp, lp) __builtin_amdgcn_global_load_lds( \
    (const __attribute__((address_space(1))) unsigned int*)(gp), \
    (__attribute__((address_space(3))) unsigned int*)(lp), 16, 0, 0)

// ---------------------------------------------------------------------------
// prep (coalesced): segment by blockIdx.  (round-3 measured version)
// ---------------------------------------------------------------------------
__global__ __launch_bounds__(256) void prep_all_kernel(
    const float* __restrict__ w0, const float* __restrict__ w1,
    const float* __restrict__ w_c, const float* __restrict__ b_c,
    const float* __restrict__ g_c, const float* __restrict__ be_c,
    u16* __restrict__ w0b, u16* __restrict__ w1b, u16* __restrict__ wcb,
    float* __restrict__ bcp, float* __restrict__ gcp, float* __restrict__ becp,
    float* __restrict__ outp)
{
    __shared__ float Lb[8][624];
    const int bid = blockIdx.x;
    const int t   = threadIdx.x;

    if (bid < 134) {                       // w0 (bid<128) or wc permute
        const bool is_w0 = (bid < 128);
        const int r0 = is_w0 ? bid * 8 : (bid - 128) * 8;
        const int nrows_src = is_w0 ? N0 : F_N;
        const float* __restrict__ src = is_w0 ? w0 : w_c;
        u16* __restrict__ dst = is_w0 ? w0b : wcb;

        for (int j = t; j < 8 * 156; j += 256) {
            const int row = j / 156;
            const int c4  = j - row * 156;
            const int n   = r0 + row;
            if (n < nrows_src)
                *(float4*)&Lb[row][c4 * 4] =
                    *(const float4*)&src[(size_t)n * FD + c4 * 4];
        }
        __syncthreads();

        for (int j = t; j < 8 * 320; j += 256) {
            const int row = j / 320;
            const int pr  = j - row * 320;
            const int n   = r0 + row;
            const int k0  = pr * 2;
            float v0 = 0.f, v1 = 0.f;
            if (n < nrows_src) {
                const int d0 = k0 & 15,       f0 = k0 >> 4;
                const int d1 = (k0 + 1) & 15, f1 = (k0 + 1) >> 4;
                if (f0 < F_N) v0 = Lb[row][d0 * F_N + f0];
                if (f1 < F_N) v1 = Lb[row][d1 * F_N + f1];
            }
            *(unsigned*)&dst[(size_t)n * KP0 + k0] = cvtpk2(v0, v1);
        }
        return;
    }
    if (bid < 390) {                       // w1 convert
        const size_t e0 = (size_t)(bid - 134) * 2048 + t * 8;
        float4 v0 = *(const float4*)(w1 + e0);
        float4 v1 = *(const float4*)(w1 + e0 + 4);
        uint4 o = { cvtpk2(v0.x, v0.y), cvtpk2(v0.z, v0.w),
                    cvtpk2(v1.x, v1.y), cvtpk2(v1.z, v1.w) };
        *(uint4*)(w1b + e0) = o;
        return;
    }
    if (bid < 398) {                       // outp zero
        const size_t e0 = (size_t)(bid - 390) * 2048 + t * 8;
        float4 z = {0.f, 0.f, 0.f, 0.f};
        *(float4*)(outp + e0)     = z;
        *(float4*)(outp + e0 + 4) = z;
        return;
    }
    if (t < 3 * NCP) {
        const int which = t / NCP, n = t - which * NCP;
        float v = 0.f;
        if (n < F_N) v = (which == 0) ? b_c[n] : (which == 1) ? g_c[n] : be_c[n];
        ((which == 0) ? bcp : (which == 1) ? gcp : becp)[n] = v;
    }
}

// ---------------------------------------------------------------------------
// Fused controller (round-3 measured version): gather -> LDS (hoisted
// x-loads), 16x48 MFMA split-K GEMM, all-wave reduce, wave-sliced
// bn/softmax/top-K rank, select-scale -> zb.
// ---------------------------------------------------------------------------
__global__ __launch_bounds__(256) void fused_controller_kernel(
    const int* __restrict__ x, const float* __restrict__ emb_table,
    const u16* __restrict__ wcb, const float* __restrict__ bcp,
    const float* __restrict__ gcp, const float* __restrict__ becp,
    u16* __restrict__ zb)
{
    __shared__ __align__(16) u16 Al[CBR * ALD];
    __shared__ float vv[CBR][49];
    __shared__ f32x4 part[4][64][3];
    __shared__ float selw[CBR][F_N];

    const int t    = threadIdx.x;
    const int wave = t >> 6;
    const int lane = t & 63;
    const int b0   = blockIdx.x * CBR;

    // ---- gather: 3 explicit slots, all x-loads hoisted before emb-loads ----
    {
        const int p0 = t, p1 = t + 256, p2 = t + 512;
        const int xi0 = x[b0 * F_N + p0];
        const int xi1 = x[b0 * F_N + p1];
        const int xi2 = (p2 < CBR * F_N) ? x[b0 * F_N + p2] : 0;
        const int pp[3] = { p0, p1, p2 };
        const int xx[3] = { xi0, xi1, xi2 };
        #pragma unroll
        for (int s = 0; s < 3; ++s) {
            const int p = pp[s];
            if (p < CBR * F_N) {
                const int row = p / F_N;
                const int f   = p - row * F_N;
                const float4* src =
                    (const float4*)(emb_table + (size_t)(xx[s] + f * V_N) * D_N);
                float4 v0 = src[0], v1 = src[1], v2 = src[2], v3 = src[3];
                uint4 o0 = { cvtpk2(v0.x, v0.y), cvtpk2(v0.z, v0.w),
                             cvtpk2(v1.x, v1.y), cvtpk2(v1.z, v1.w) };
                uint4 o1 = { cvtpk2(v2.x, v2.y), cvtpk2(v2.z, v2.w),
                             cvtpk2(v3.x, v3.y), cvtpk2(v3.z, v3.w) };
                *(uint4*)&Al[row * ALD + f * D_N]     = o0;
                *(uint4*)&Al[row * ALD + f * D_N + 8] = o1;
            }
        }
    }
    __syncthreads();

    const int m = lane & 15;
    const int q = lane >> 4;
    f32x4 acc0 = {}, acc1 = {}, acc2 = {};
    {
        const u16* ap  = &Al[m * ALD + wave * 160 + q * 8];
        const u16* bp0 = wcb + (size_t)(0  + m) * KP0 + wave * 160 + q * 8;
        const u16* bp1 = wcb + (size_t)(16 + m) * KP0 + wave * 160 + q * 8;
        const u16* bp2 = wcb + (size_t)(32 + m) * KP0 + wave * 160 + q * 8;
        #pragma unroll
        for (int k = 0; k < 5; ++k) {
            bf16x8 af = *(const bf16x8*)ap;
            bf16x8 b0 = *(const bf16x8*)bp0;
            bf16x8 b1 = *(const bf16x8*)bp1;
            bf16x8 b2 = *(const bf16x8*)bp2;
            acc0 = __builtin_amdgcn_mfma_f32_16x16x32_bf16(af, b0, acc0, 0, 0, 0);
            acc1 = __builtin_amdgcn_mfma_f32_16x16x32_bf16(af, b1, acc1, 0, 0, 0);
            acc2 = __builtin_amdgcn_mfma_f32_16x16x32_bf16(af, b2, acc2, 0, 0, 0);
            ap += 32; bp0 += 32; bp1 += 32; bp2 += 32;
        }
    }
    part[wave][lane][0] = acc0;
    part[wave][lane][1] = acc1;
    part[wave][lane][2] = acc2;
    __syncthreads();

    {
        f32x4 r0 = part[0][lane][0] + part[1][lane][0] + part[2][lane][0] + part[3][lane][0];
        f32x4 r1 = part[0][lane][1] + part[1][lane][1] + part[2][lane][1] + part[3][lane][1];
        f32x4 r2 = part[0][lane][2] + part[1][lane][2] + part[2][lane][2] + part[3][lane][2];

        const float rs = rsqrtf(1.0f + 1e-5f);
        if (q == wave) {
            #pragma unroll
            for (int j = 0; j < 3; ++j) {
                const f32x4 a = (j == 0) ? r0 : (j == 1) ? r1 : r2;
                const int n = j * 16 + m;
                const float gn = gcp[n] * rs;
                const float bn = becp[n];
                const float bi = bcp[n];
                #pragma unroll
                for (int r = 0; r < 4; ++r)
                    vv[wave * 4 + r][n] = fmaxf(fmaf(gn, a[r] + bi, bn), 0.f);
            }
        }
    }
    __syncthreads();

    {
        const int row = wave * 4 + (lane >> 4);
        const int fl  = lane & 15;
        float e[3] = {0.f, 0.f, 0.f};
        float mloc = -1e30f;
        #pragma unroll
        for (int it = 0; it < 3; ++it) {
            const int f = fl + 16 * it;
            if (f < F_N) { e[it] = vv[row][f]; mloc = fmaxf(mloc, e[it]); }
        }
        mloc = fmaxf(mloc, __shfl_xor(mloc, 1, 64));
        mloc = fmaxf(mloc, __shfl_xor(mloc, 2, 64));
        mloc = fmaxf(mloc, __shfl_xor(mloc, 4, 64));
        mloc = fmaxf(mloc, __shfl_xor(mloc, 8, 64));
        float sloc = 0.f;
        #pragma unroll
        for (int it = 0; it < 3; ++it) {
            const int f = fl + 16 * it;
            if (f < F_N) { e[it] = expf(e[it] - mloc); sloc += e[it]; }
        }
        sloc += __shfl_xor(sloc, 1, 64);
        sloc += __shfl_xor(sloc, 2, 64);
        sloc += __shfl_xor(sloc, 4, 64);
        sloc += __shfl_xor(sloc, 8, 64);
        const float inv = 1.f / sloc;
        #pragma unroll
        for (int it = 0; it < 3; ++it) {
            const int f = fl + 16 * it;
            if (f < F_N) vv[row][f] = e[it];
        }

        int rank[3] = {};
        for (int gg = 0; gg < F_N; ++gg) {
            const float o = vv[row][gg];
            #pragma unroll
            for (int it = 0; it < 3; ++it) {
                const int f = fl + 16 * it;
                if (f < F_N)
                    rank[it] += (o > e[it] || (o == e[it] && gg < f)) ? 1 : 0;
            }
        }
        #pragma unroll
        for (int it = 0; it < 3; ++it) {
            const int f = fl + 16 * it;
            if (f < F_N)
                selw[row][f] = (rank[it] < K_SEL) ? e[it] * inv : 0.f;
        }
    }
    __syncthreads();

    // zb write: row-major work mapping, packed converts.
    for (int gp = t; gp < CBR * 40; gp += 256) {
        const int row  = gp / 40;
        const int slot = gp - row * 40;
        u16* dst = zb + (size_t)(b0 + row) * KP0 + slot * D_N;
        uint4 o0 = {0u,0u,0u,0u}, o1 = {0u,0u,0u,0u};
        if (slot < F_N) {
            const float w = selw[row][slot];
            u16x8 a0 = *(u16x8*)&Al[row * ALD + slot * D_N];
            u16x8 a1 = *(u16x8*)&Al[row * ALD + slot * D_N + 8];
            o0 = (uint4){ cvtpk2(bf2f(a0[0]) * w, bf2f(a0[1]) * w),
                          cvtpk2(bf2f(a0[2]) * w, bf2f(a0[3]) * w),
                          cvtpk2(bf2f(a0[4]) * w, bf2f(a0[5]) * w),
                          cvtpk2(bf2f(a0[6]) * w, bf2f(a0[7]) * w) };
            o1 = (uint4){ cvtpk2(bf2f(a1[0]) * w, bf2f(a1[1]) * w),
                          cvtpk2(bf2f(a1[2]) * w, bf2f(a1[3]) * w),
                          cvtpk2(bf2f(a1[4]) * w, bf2f(a1[5]) * w),
                          cvtpk2(bf2f(a1[6]) * w, bf2f(a1[7]) * w) };
        }
        *(uint4*)dst       = o0;
        *(uint4*)(dst + 8) = o1;
    }
}

// ---------------------------------------------------------------------------
// MFMA GEMM (round-3 measured 256x128 2-phase counted-vmcnt pipeline) +
// NEW: XCD-aware block swizzle. Dispatch round-robins consecutive flat block
// ids across the 8 XCDs; we remap so XCD k owns a contiguous 8-m-tile chunk
// of A (gemm0: 2.62 MB zb + 1.31 MB w0b < 4 MB L2) across ALL n-tiles. With
// 2 blocks/CU all of an XCD's blocks are co-resident, so the (N/BN)-pass
// A re-reads hit the XCD-private L2 instead of L3. Bijective: nwg in
// {512,256}, both % 8 == 0, MT=64 fixed.
// ---------------------------------------------------------------------------
template<int MODE>
__global__ __launch_bounds__(512) void gemm_mfma_bn_relu(
    const u16* __restrict__ A, const u16* __restrict__ W,
    const float* __restrict__ bias, const float* __restrict__ g,
    const float* __restrict__ be, u16* __restrict__ Cout,
    int M, int N, int Kp,
    const float* __restrict__ w_out, float* __restrict__ outp)
{
    // 3 stages x (A 8192 u16 + B 4096 u16) = 72KB.
    __shared__ __align__(16) u16 SM[3 * 12288];

    const int t    = threadIdx.x;
    const int wave = t >> 6;
    const int lane = t & 63;
    const int wm   = wave >> 1, wn = wave & 1;   // 4 m-waves x 2 n-waves

    // XCD swizzle: flat id in HW dispatch order (x fastest).
    const int flat = blockIdx.y * gridDim.x + blockIdx.x;
    const int xcd  = flat & 7;
    const int jj   = flat >> 3;
    const int mt   = xcd * 8 + (jj & 7);   // MT=64 m-tiles, 8 per XCD
    const int nt   = jj >> 3;
    const int m0   = mt * 256;
    const int n0   = nt * 128;

    const int rA0 = t >> 2;
    const int cA0 = (t & 3) ^ ((rA0 >> 1) & 3);
    const int rA1 = 128 + rA0;
    const int cA1 = (t & 3) ^ ((rA1 >> 1) & 3);
    const u16* gA0 = A + (size_t)(m0 + rA0) * Kp + cA0 * 8;
    const u16* gA1 = A + (size_t)(m0 + rA1) * Kp + cA1 * 8;
    const u16* gB  = W + (size_t)(n0 + rA0) * Kp + cA0 * 8;
    const int dA0 = t * 8, dA1 = 4096 + t * 8, dB = 8192 + t * 8;

    const int q    = lane >> 4;
    const int lr16 = lane & 15;

    int aoff[4], boff[4];
    #pragma unroll
    for (int i = 0; i < 4; ++i) {
        int ra = wm * 64 + i * 16 + lr16;
        aoff[i] = ra * 32 + ((q ^ ((ra >> 1) & 3)) * 8);
        int rb = wn * 64 + i * 16 + lr16;
        boff[i] = rb * 32 + ((q ^ ((rb >> 1) & 3)) * 8);
    }

    const int NIT = Kp >> 5;     // 20 (GEMM0) / 32 (GEMM1)

    // prologue: stage k-blocks 0,1 into buffers 0,1  (6 GLDs outstanding)
    GLD16(gA0, SM + dA0);
    GLD16(gA1, SM + dA1);
    GLD16(gB,  SM + dB);
    gA0 += 32; gA1 += 32; gB += 32;
    GLD16(gA0, SM + 12288 + dA0);
    GLD16(gA1, SM + 12288 + dA1);
    GLD16(gB,  SM + 12288 + dB);
    gA0 += 32; gA1 += 32; gB += 32;

    f32x4 acc[4][4] = {};
    int cur = 0, stg = 2;

    for (int it = 0; it < NIT - 1; ++it) {
        asm volatile("s_waitcnt vmcnt(3)" ::: "memory");
        __builtin_amdgcn_s_barrier();
        __builtin_amdgcn_sched_barrier(0);

        const u16* ac = SM + cur * 12288;
        const u16* bc = ac + 8192;

        // phase 0: 6 ds_reads, GLD issue in their shadow, then 8 MFMA
        bf16x8 af0 = *(const bf16x8*)(ac + aoff[0]);
        bf16x8 af1 = *(const bf16x8*)(ac + aoff[1]);
        bf16x8 b0v = *(const bf16x8*)(bc + boff[0]);
        bf16x8 b1v = *(const bf16x8*)(bc + boff[1]);
        bf16x8 b2v = *(const bf16x8*)(bc + boff[2]);
        bf16x8 b3v = *(const bf16x8*)(bc + boff[3]);

        if (it + 2 < NIT) {
            u16* s = SM + stg * 12288;
            GLD16(gA0, s + dA0);
            GLD16(gA1, s + dA1);
            GLD16(gB,  s + dB);
            gA0 += 32; gA1 += 32; gB += 32;
        }

        asm volatile("s_waitcnt lgkmcnt(0)" ::: "memory");
        __builtin_amdgcn_sched_barrier(0);
        __builtin_amdgcn_s_setprio(1);
        acc[0][0] = __builtin_amdgcn_mfma_f32_16x16x32_bf16(af0, b0v, acc[0][0], 0, 0, 0);
        acc[0][1] = __builtin_amdgcn_mfma_f32_16x16x32_bf16(af0, b1v, acc[0][1], 0, 0, 0);
        acc[0][2] = __builtin_amdgcn_mfma_f32_16x16x32_bf16(af0, b2v, acc[0][2], 0, 0, 0);
        acc[0][3] = __builtin_amdgcn_mfma_f32_16x16x32_bf16(af0, b3v, acc[0][3], 0, 0, 0);
        acc[1][0] = __builtin_amdgcn_mfma_f32_16x16x32_bf16(af1, b0v, acc[1][0], 0, 0, 0);
        acc[1][1] = __builtin_amdgcn_mfma_f32_16x16x32_bf16(af1, b1v, acc[1][1], 0, 0, 0);
        acc[1][2] = __builtin_amdgcn_mfma_f32_16x16x32_bf16(af1, b2v, acc[1][2], 0, 0, 0);
        acc[1][3] = __builtin_amdgcn_mfma_f32_16x16x32_bf16(af1, b3v, acc[1][3], 0, 0, 0);
        __builtin_amdgcn_s_setprio(0);
        __builtin_amdgcn_s_barrier();     // phase alignment across waves

        // phase 1: 2 ds_reads, 8 MFMA
        bf16x8 af2 = *(const bf16x8*)(ac + aoff[2]);
        bf16x8 af3 = *(const bf16x8*)(ac + aoff[3]);
        asm volatile("s_waitcnt lgkmcnt(0)" ::: "memory");
        __builtin_amdgcn_sched_barrier(0);
        __builtin_amdgcn_s_setprio(1);
        acc[2][0] = __builtin_amdgcn_mfma_f32_16x16x32_bf16(af2, b0v, acc[2][0], 0, 0, 0);
        acc[2][1] = __builtin_amdgcn_mfma_f32_16x16x32_bf16(af2, b1v, acc[2][1], 0, 0, 0);
        acc[2][2] = __builtin_amdgcn_mfma_f32_16x16x32_bf16(af2, b2v, acc[2][2], 0, 0, 0);
        acc[2][3] = __builtin_amdgcn_mfma_f32_16x16x32_bf16(af2, b3v, acc[2][3], 0, 0, 0);
        acc[3][0] = __builtin_amdgcn_mfma_f32_16x16x32_bf16(af3, b0v, acc[3][0], 0, 0, 0);
        acc[3][1] = __builtin_amdgcn_mfma_f32_16x16x32_bf16(af3, b1v, acc[3][1], 0, 0, 0);
        acc[3][2] = __builtin_amdgcn_mfma_f32_16x16x32_bf16(af3, b2v, acc[3][2], 0, 0, 0);
        acc[3][3] = __builtin_amdgcn_mfma_f32_16x16x32_bf16(af3, b3v, acc[3][3], 0, 0, 0);
        __builtin_amdgcn_s_setprio(0);

        cur = (cur == 2) ? 0 : cur + 1;
        stg = (stg == 2) ? 0 : stg + 1;
    }

    // peeled final iteration: only 3 GLDs remain outstanding -> full drain
    asm volatile("s_waitcnt vmcnt(0)" ::: "memory");
    __builtin_amdgcn_s_barrier();
    __builtin_amdgcn_sched_barrier(0);
    {
        const u16* ac = SM + cur * 12288;
        const u16* bc = ac + 8192;
        bf16x8 af[4], bfr[4];
        #pragma unroll
        for (int i = 0; i < 4; ++i) af[i]  = *(const bf16x8*)(ac + aoff[i]);
        #pragma unroll
        for (int j = 0; j < 4; ++j) bfr[j] = *(const bf16x8*)(bc + boff[j]);
        __builtin_amdgcn_s_setprio(1);
        #pragma unroll
        for (int i = 0; i < 4; ++i)
            #pragma unroll
            for (int j = 0; j < 4; ++j)
                acc[i][j] = __builtin_amdgcn_mfma_f32_16x16x32_bf16(
                    af[i], bfr[j], acc[i][j], 0, 0, 0);
        __builtin_amdgcn_s_setprio(0);
    }

    const float rs = rsqrtf(1.0f + 1e-5f);
    if (MODE == 0) {
        // stage C tile in LDS (stride 136 u16), packed bf16 converts,
        // then 16B/lane coalesced stores.
        __syncthreads();            // all waves done reading As/Bs
        u16* Cs = SM;               // 256 x 136 u16 = 69632 B
        #pragma unroll
        for (int j = 0; j < 4; ++j) {
            const int nl = wn * 64 + j * 16 + lr16;
            const int n  = n0 + nl;
            const float bn_g = g[n] * rs;
            const float bn_b = be[n];
            const float bi   = bias[n];
            #pragma unroll
            for (int i = 0; i < 4; ++i) {
                const int mlb = wm * 64 + i * 16 + q * 4;
                float v0 = fmaxf(fmaf(bn_g, acc[i][j][0] + bi, bn_b), 0.f);
                float v1 = fmaxf(fmaf(bn_g, acc[i][j][1] + bi, bn_b), 0.f);
                float v2 = fmaxf(fmaf(bn_g, acc[i][j][2] + bi, bn_b), 0.f);
                float v3 = fmaxf(fmaf(bn_g, acc[i][j][3] + bi, bn_b), 0.f);
                unsigned pA = cvtpk2(v0, v1);
                unsigned pB = cvtpk2(v2, v3);
                Cs[(mlb + 0) * 136 + nl] = (u16)pA;
                Cs[(mlb + 1) * 136 + nl] = (u16)(pA >> 16);
                Cs[(mlb + 2) * 136 + nl] = (u16)pB;
                Cs[(mlb + 3) * 136 + nl] = (u16)(pB >> 16);
            }
        }
        __syncthreads();
        #pragma unroll
        for (int s = 0; s < 8; ++s) {
            const int chunk = s * 512 + t;      // 0..4095
            const int row   = chunk >> 4;
            const int col   = (chunk & 15) << 3;
            *(u16x8*)&Cout[(size_t)(m0 + row) * N + n0 + col] =
                *(const u16x8*)&Cs[row * 136 + col];
        }
    } else {
        float s[4][4] = {};
        #pragma unroll
        for (int j = 0; j < 4; ++j) {
            const int n = n0 + wn * 64 + j * 16 + lr16;
            const float bn_g = g[n] * rs;
            const float bn_b = be[n];
            const float bi   = bias[n];
            const float wo   = w_out[n];
            #pragma unroll
            for (int i = 0; i < 4; ++i)
                #pragma unroll
                for (int r = 0; r < 4; ++r) {
                    float v = acc[i][j][r] + bi;
                    v = fmaxf(fmaf(bn_g, v, bn_b), 0.f);
                    s[i][r] = fmaf(v, wo, s[i][r]);
                }
        }
        #pragma unroll
        for (int i = 0; i < 4; ++i)
            #pragma unroll
            for (int r = 0; r < 4; ++r) {
                float v = s[i][r];
                v += __shfl_xor(v, 1, 64);
                v += __shfl_xor(v, 2, 64);
                v += __shfl_xor(v, 4, 64);
                v += __shfl_xor(v, 8, 64);
                s[i][r] = v;
            }
        if (lr16 == 0) {
            #pragma unroll
            for (int i = 0; i < 4; ++i) {
                const int mbase = m0 + wm * 64 + i * 16 + q * 4;
                #pragma unroll
                for (int r = 0; r < 4; ++r)
                    atomicAdd(&outp[mbase + r], s[i][r]);
            }
        }
    }
}

// ---------------------------------------------------------------------------
// out[b] = sigmoid(outp[b] + b_out)
// ---------------------------------------------------------------------------
__global__ __launch_bounds__(256) void sigmoid_kernel(
    const float* __restrict__ outp, const float* __restrict__ b_out,
    float* __restrict__ out)
{
    const int b = blockIdx.x * 256 + threadIdx.x;
    out[b] = 1.f / (1.f + expf(-(outp[b] + b_out[0])));
}

// ---------------------------------------------------------------------------
extern "C" void kernel_launch(void* const* d_in, const int* in_sizes, int n_in,
                              void* d_out, int out_size, void* d_ws, size_t ws_size,
                              hipStream_t stream)
{
    const int*   x     = (const int*)  d_in[0];
    const float* emb   = (const float*)d_in[1];
    const float* w_c   = (const float*)d_in[2];
    const float* b_c   = (const float*)d_in[3];
    const float* g_c   = (const float*)d_in[4];
    const float* be_c  = (const float*)d_in[5];
    const float* w0    = (const float*)d_in[6];
    const float* b0    = (const float*)d_in[7];
    const float* g0    = (const float*)d_in[8];
    const float* be0   = (const float*)d_in[9];
    const float* w1    = (const float*)d_in[10];
    const float* b1    = (const float*)d_in[11];
    const float* g1    = (const float*)d_in[12];
    const float* be1   = (const float*)d_in[13];
    const float* w_out = (const float*)d_in[14];
    const float* b_out = (const float*)d_in[15];
    float* out = (float*)d_out;

    // workspace layout (~57 MB)
    u16*   zb    = (u16*)d_ws;                          // B*640*2  = 20.97 MB
    u16*   w0b   = zb    + (size_t)B_SZ * KP0;          // 1.31 MB
    u16*   h0b   = w0b   + (size_t)N0 * KP0;            // 33.55 MB
    u16*   w1b   = h0b   + (size_t)B_SZ * N0;           // 1.05 MB
    u16*   wcb   = w1b   + (size_t)N1 * N0;             // 0.06 MB
    float* outp  = (float*)(wcb + (size_t)NCP * KP0);   // 64 KB
    float* bcp   = outp + B_SZ;
    float* gcp   = bcp + NCP;
    float* becp  = gcp + NCP;

    prep_all_kernel<<<399, 256, 0, stream>>>(
        w0, w1, w_c, b_c, g_c, be_c, w0b, w1b, wcb, bcp, gcp, becp, outp);

    fused_controller_kernel<<<B_SZ / CBR, 256, 0, stream>>>(
        x, emb, wcb, bcp, gcp, becp, zb);

    gemm_mfma_bn_relu<0><<<dim3(B_SZ / 256, N0 / 128), 512, 0, stream>>>(
        zb, w0b, b0, g0, be0, h0b, B_SZ, N0, KP0, nullptr, nullptr);

    gemm_mfma_bn_relu<1><<<dim3(B_SZ / 256, N1 / 128), 512, 0, stream>>>(
        h0b, w1b, b1, g1, be1, nullptr, B_SZ, N1, N0, w_out, outp);

    sigmoid_kernel<<<B_SZ / 256, 256, 0, stream>>>(outp, b_out, out);
}